// Round 1
// 257.231 us; speedup vs baseline: 1.1079x; 1.1079x over previous
//
#include <hip/hip_runtime.h>
#include <hip/hip_bf16.h>
#include <math.h>

#define B_  32
#define N_  512
#define C_  384
#define H_  6
#define HD_ 64
#define M_  (B_*N_)   // 16384 rows

typedef __attribute__((ext_vector_type(8))) short bfrag;            // 8 bf16 (4 VGPRs)
typedef __attribute__((ext_vector_type(8))) unsigned short u16x8;   // 8 bf16 loads
typedef __attribute__((ext_vector_type(4))) float f32x4;            // mfma C/D

__device__ __forceinline__ unsigned short f2bfu(float f){
  unsigned int u = __float_as_uint(f);
  u += 0x7fffu + ((u >> 16) & 1u);   // round-to-nearest-even
  return (unsigned short)(u >> 16);
}
__device__ __forceinline__ float bf2f(unsigned short u){
  return __uint_as_float(((unsigned int)u) << 16);
}
__device__ __forceinline__ bfrag cvt8(float4 a, float4 b){
  bfrag r;
  r[0]=(short)f2bfu(a.x); r[1]=(short)f2bfu(a.y); r[2]=(short)f2bfu(a.z); r[3]=(short)f2bfu(a.w);
  r[4]=(short)f2bfu(b.x); r[5]=(short)f2bfu(b.y); r[6]=(short)f2bfu(b.z); r[7]=(short)f2bfu(b.w);
  return r;
}
// async global->LDS, 16B per lane; LDS dest must be wave-uniform base + lane*16
__device__ __forceinline__ void gload_lds16(const unsigned short* gp, unsigned short* lp){
  __builtin_amdgcn_global_load_lds(
      (const __attribute__((address_space(1))) void*)gp,
      (__attribute__((address_space(3))) void*)lp, 16, 0, 0);
}

// ---------------- params ----------------
__global__ void param_kernel(const float* __restrict__ scale_p,
                             const float* __restrict__ power_p,
                             float* __restrict__ scale_inv,
                             float* __restrict__ power){
  int t = threadIdx.x;
  if (t < C_){
    float s  = scale_p[t];
    scale_inv[t] = 1.0f / log1pf(expf(s));   // 1/softplus
  }
  if (t < H_*HD_){
    float p = power_p[t];
    power[t] = 1.0f + 4.0f / (1.0f + expf(-p));
  }
}

__global__ void sentinel_kernel(float* __restrict__ out, int n){
  int i = blockIdx.x*256 + threadIdx.x;
  if (i < n) out[i] = 1.0e9f;
}

// ---------------- bf16 conversion prepass: x (3072 blk), y (3072), W (288) ----------------
__global__ __launch_bounds__(256) void cvt_bf16_kernel(
    const float* __restrict__ x, const float* __restrict__ y,
    const float* __restrict__ W,
    unsigned short* __restrict__ xb, unsigned short* __restrict__ yb,
    unsigned short* __restrict__ Wb)
{
  const int bid = blockIdx.x;
  const float* src; unsigned short* dst; int base;
  if (bid < 3072)      { src = x; dst = xb; base = bid; }
  else if (bid < 6144) { src = y; dst = yb; base = bid - 3072; }
  else                 { src = W; dst = Wb; base = bid - 6144; }
  const size_t i0 = ((size_t)base*256 + threadIdx.x)*8;
  float4 a = *reinterpret_cast<const float4*>(src + i0);
  float4 b = *reinterpret_cast<const float4*>(src + i0 + 4);
  *reinterpret_cast<bfrag*>(dst + i0) = cvt8(a, b);
}

// ---------------- fused qkvg GEMM: [16384 x 1536] = A_mode @ Wb^T, bf16 MFMA ----------------
// grid (12, 128): col block 0..11 (mode = bx/3), row block 0..127.
// m97 structure: 128x128 tile, BK=32, global_load_lds dwordx4, double-buffered LDS,
// one barrier per K-step (prefetch t+1 issued before compute t).
__global__ __launch_bounds__(256) void gemm_qkvg(
    const unsigned short* __restrict__ xb, const unsigned short* __restrict__ yb,
    const unsigned short* __restrict__ Wb, const float* __restrict__ bias,
    const float* __restrict__ pe, const float* __restrict__ scale_inv,
    float* __restrict__ q, float* __restrict__ k,
    unsigned short* __restrict__ v, unsigned short* __restrict__ g)
{
  __shared__ unsigned short As[2][4096];   // [128][32] bf16 per buffer, linear
  __shared__ unsigned short Bs[2][4096];

  const int tid  = threadIdx.x;
  const int row0 = blockIdx.y * 128;
  const int col0 = blockIdx.x * 128;       // global col in [0,1536)
  const int mode = blockIdx.x / 3;         // 0:q(y) 1:k 2:v 3:g
  const unsigned short* Ab = (mode == 0) ? yb : xb;

  const int wave = tid >> 6, lane = tid & 63;
  const int wm = (wave >> 1) * 64, wn = (wave & 1) * 64;
  const int fr = lane & 15, quad = lane >> 4;
  const int srr = tid >> 2;                // staging row 0..63
  const int skc = (tid & 3) * 8;           // staging col 0,8,16,24

  const unsigned short* ga0 = &Ab[(size_t)(row0 + srr)*C_ + skc];
  const unsigned short* gb0 = &Wb[(size_t)(col0 + srr)*C_ + skc];
  const size_t gstep = (size_t)64*C_;

  f32x4 acc[4][4] = {};

  // prologue: stage k0=0 into buffer 0
  gload_lds16(ga0,         &As[0][tid*8]);
  gload_lds16(ga0 + gstep, &As[0][2048 + tid*8]);
  gload_lds16(gb0,         &Bs[0][tid*8]);
  gload_lds16(gb0 + gstep, &Bs[0][2048 + tid*8]);
  __syncthreads();   // drains vmcnt -> buffer 0 ready

  #pragma unroll 2
  for (int t = 0; t < 12; t++){
    const int cur = t & 1;
    if (t < 11){
      const int k0 = (t+1)*32;
      gload_lds16(ga0 + k0,         &As[cur^1][tid*8]);
      gload_lds16(ga0 + gstep + k0, &As[cur^1][2048 + tid*8]);
      gload_lds16(gb0 + k0,         &Bs[cur^1][tid*8]);
      gload_lds16(gb0 + gstep + k0, &Bs[cur^1][2048 + tid*8]);
    }
    bfrag af[4], bf[4];
    #pragma unroll
    for (int f = 0; f < 4; f++){
      af[f] = *reinterpret_cast<const bfrag*>(&As[cur][(wm + f*16 + fr)*32 + quad*8]);
      bf[f] = *reinterpret_cast<const bfrag*>(&Bs[cur][(wn + f*16 + fr)*32 + quad*8]);
    }
    #pragma unroll
    for (int i=0;i<4;i++)
      #pragma unroll
      for (int j=0;j<4;j++)
        acc[i][j] = __builtin_amdgcn_mfma_f32_16x16x32_bf16(af[i], bf[j], acc[i][j], 0, 0, 0);
    __syncthreads();   // drains vmcnt (prefetch landed) + all waves done reading cur
  }

  // epilogue (mode uniform per block)
  const int cbase = col0 - mode*384;
  #pragma unroll
  for (int i = 0; i < 4; i++){
    const int rowb = row0 + wm + i*16 + quad*4;
    #pragma unroll
    for (int j = 0; j < 4; j++){
      const int cc = cbase + wn + j*16 + fr;       // col within [0,384)
      const float bcol = bias[mode*384 + cc];
      if (mode == 0){
        const float scv = scale_inv[cc];
        #pragma unroll
        for (int r = 0; r < 4; r++)
          q[(size_t)(rowb + r)*C_ + cc] = (acc[i][j][r] + bcol) * scv;
      } else if (mode == 1){
        const float scv = scale_inv[cc];
        #pragma unroll
        for (int r = 0; r < 4; r++){
          const int row = rowb + r;
          const int n = row & (N_-1);
          k[(size_t)row*C_ + cc] = (acc[i][j][r] + bcol + pe[n*C_ + cc]) * scv;
        }
      } else if (mode == 2){
        #pragma unroll
        for (int r = 0; r < 4; r++)
          v[(size_t)(rowb + r)*C_ + cc] = f2bfu(acc[i][j][r] + bcol);
      } else {
        #pragma unroll
        for (int r = 0; r < 4; r++)
          g[(size_t)(rowb + r)*C_ + cc] = f2bfu(acc[i][j][r] + bcol);
      }
    }
  }
}

// ---------------- attention, MFMA: one block per (b,h), 512 threads (8 waves) ----------------
#define NC_ 256
__global__ __launch_bounds__(512) void attn_kernel(
    const float* __restrict__ q, const float* __restrict__ k,
    const unsigned short* __restrict__ v, const float* __restrict__ power,
    float* __restrict__ xa)
{
  const int bh = blockIdx.x;
  const int b = bh / H_, h = bh % H_;
  __shared__ float pw[64];
  __shared__ __align__(16) unsigned short smem[54912];  // 109,824 B
  unsigned short* kfT  = smem;                  // [128][264] phase A
  unsigned short* vT   = smem + 33792;          // [80][264]  phase A
  unsigned short* kvBT = smem;                  // [80][136]  phase B (alias)
  unsigned short* qf   = smem + 33792;          // [128][136] phase B (alias)

  const int tid = threadIdx.x;
  const int wave = tid >> 6, lane = tid & 63;
  const int fr = lane & 15, quad = lane >> 4;
  if (tid < 64) pw[tid] = power[h*HD_ + tid];

  const float*          kbase = k + (size_t)b*N_*C_ + h*HD_;
  const unsigned short* vbase = v + (size_t)b*N_*C_ + h*HD_;

  // init vT rows 64..79 (ones column + zeros) — persists across both chunks
  for (int i = tid; i < 16*NC_; i += 512){
    int e = 64 + (i >> 8);
    int nl = i & (NC_-1);
    vT[e*264 + nl] = (e == 64) ? (unsigned short)0x3F80 : (unsigned short)0;
  }
  __syncthreads();

  f32x4 acc[5] = {};
  for (int chunk = 0; chunk < 2; chunk++){
    const int n0 = chunk * NC_;
    for (int it = 0; it < 32; it++){
      int flat = it*512 + tid;
      int c = flat & 63, nl = flat >> 6;
      float kval = kbase[(size_t)(n0+nl)*C_ + c];
      float p = pw[c];
      float ax = fabsf(kval);
      float pv = (ax > 0.0f) ? exp2f(p * log2f(ax)) : 0.0f;
      kfT[c*264 + nl]      = f2bfu((kval > 0.0f) ? pv : 0.0f);
      kfT[(64+c)*264 + nl] = f2bfu((kval < 0.0f) ? pv : 0.0f);
      vT[c*264 + nl] = vbase[(size_t)(n0+nl)*C_ + c];
    }
    __syncthreads();
    for (int kk = 0; kk < NC_/32; kk++){
      int ko = kk*32 + quad*8;
      bfrag af = *reinterpret_cast<const bfrag*>(&kfT[(wave*16 + fr)*264 + ko]);
      #pragma unroll
      for (int j = 0; j < 5; j++){
        bfrag bf = *reinterpret_cast<const bfrag*>(&vT[(j*16 + fr)*264 + ko]);
        acc[j] = __builtin_amdgcn_mfma_f32_16x16x32_bf16(af, bf, acc[j], 0, 0, 0);
      }
    }
    __syncthreads();
  }

  // write kvBT (scaled), with d^64 flip for e>=32; rows 64/65 = z-vectors
  const float invN = 1.0f / (float)N_;
  {
    const int dbase = wave*16 + quad*4;
    #pragma unroll
    for (int j = 0; j < 4; j++){
      const int e = j*16 + fr;
      const int dd = (e < 32) ? dbase : (dbase ^ 64);
      ushort4 w4;
      w4.x = f2bfu(acc[j][0] * invN);
      w4.y = f2bfu(acc[j][1] * invN);
      w4.z = f2bfu(acc[j][2] * invN);
      w4.w = f2bfu(acc[j][3] * invN);
      *reinterpret_cast<ushort4*>(&kvBT[e*136 + dd]) = w4;
    }
    if (fr == 0){
      ushort4 wk;
      wk.x = f2bfu(acc[4][0] * invN);
      wk.y = f2bfu(acc[4][1] * invN);
      wk.z = f2bfu(acc[4][2] * invN);
      wk.w = f2bfu(acc[4][3] * invN);
      *reinterpret_cast<ushort4*>(&kvBT[64*136 + dbase]) = wk;          // km[d]
      *reinterpret_cast<ushort4*>(&kvBT[65*136 + (dbase^64)]) = wk;     // km at flipped d
    }
  }
  __syncthreads();

  // phase B: 4 m-chunks of 128 rows
  const float* qbase = q + (size_t)b*N_*C_ + h*HD_;
  float* xabase = xa + (size_t)b*N_*C_ + h*HD_;
  for (int mc = 0; mc < 4; mc++){
    const int m0 = mc * 128;
    for (int it = 0; it < 16; it++){
      int flat = it*512 + tid;
      int c = flat & 63, nl = flat >> 6;
      float qval = qbase[(size_t)(m0+nl)*C_ + c];
      float p = pw[c];
      float ax = fabsf(qval);
      float pv = (ax > 0.0f) ? exp2f(p * log2f(ax)) : 0.0f;
      qf[nl*136 + c]      = f2bfu((qval > 0.0f) ? pv : 0.0f);
      qf[nl*136 + 64 + c] = f2bfu((qval < 0.0f) ? pv : 0.0f);
    }
    __syncthreads();
    f32x4 a2[5] = {};
    for (int kk = 0; kk < 4; kk++){
      int ko = kk*32 + quad*8;
      bfrag af = *reinterpret_cast<const bfrag*>(&qf[(wave*16 + fr)*136 + ko]);
      #pragma unroll
      for (int j = 0; j < 5; j++){
        bfrag bf = *reinterpret_cast<const bfrag*>(&kvBT[(j*16 + fr)*136 + ko]);
        a2[j] = __builtin_amdgcn_mfma_f32_16x16x32_bf16(af, bf, a2[j], 0, 0, 0);
      }
    }
    #pragma unroll
    for (int r = 0; r < 4; r++){
      const float zsim = __shfl(a2[4][r], quad*16);
      const float zopp = __shfl(a2[4][r], quad*16 + 1);
      const int n = m0 + wave*16 + quad*4 + r;
      #pragma unroll
      for (int j = 0; j < 4; j++){
        const int e = j*16 + fr;
        const float z = (e < 32) ? zsim : zopp;
        xabase[(size_t)n*C_ + e] = a2[j][r] / (z + 1e-6f);
      }
    }
    __syncthreads();   // before next m-chunk overwrites qf
  }
}

// ---------------- conv: ch-halves, 8-wide x-rows in registers, coalesced RMW ----------------
__global__ __launch_bounds__(512) void conv_kernel(
    const unsigned short* __restrict__ v, const float* __restrict__ dwc_w,
    const float* __restrict__ dwc_b, float* __restrict__ xa)
{
  const int bh = blockIdx.x;
  const int b = bh / H_, h = bh % H_;
  __shared__ float vol[32][521];   // 66.7 KB
  __shared__ float wv[32][126];    // 16.1 KB
  __shared__ float wb[32];
  const int tid = threadIdx.x;
  const unsigned short* vbase = v + (size_t)b*N_*C_ + h*HD_;
  float* xabatch = xa + (size_t)b*N_*C_ + (size_t)h*N_*HD_;

  for (int half = 0; half < 2; half++){
    const int ch0 = half * 32;
    // stage v half: 32 ch x 512 n
    for (int it = 0; it < 32; it++){
      int flat = it*512 + tid;
      int cl = flat & 31, n = flat >> 5;
      vol[cl][n] = bf2f(vbase[(size_t)n*C_ + ch0 + cl]);
    }
    // stage weights
    for (int i = tid; i < 32*125; i += 512){
      int ch = i / 125, wi = i - ch*125;
      wv[ch][wi] = dwc_w[(ch0+ch)*125 + wi];
    }
    if (tid < 32) wb[tid] = dwc_b[ch0 + tid];
    __syncthreads();

    for (int t = 0; t < 4; t++){
      const int task = t*512 + tid;
      const int ch = task & 31;
      const int zy = task >> 5;          // 0..63
      const int z = zy >> 3, yc = zy & 7;
      float o[8];
      const float bias = wb[ch];
      #pragma unroll
      for (int xx = 0; xx < 8; xx++) o[xx] = bias;
      #pragma unroll
      for (int kd = 0; kd < 5; kd++){
        const int zz = z + kd - 2;
        if ((unsigned)zz >= 8u) continue;
        #pragma unroll
        for (int kh = 0; kh < 5; kh++){
          const int yy = yc + kh - 2;
          if ((unsigned)yy >= 8u) continue;
          const float* row = &vol[ch][zz*64 + yy*8];
          float rr[8];
          #pragma unroll
          for (int xx = 0; xx < 8; xx++) rr[xx] = row[xx];
          const float* wrow = &wv[ch][kd*25 + kh*5];
          float w5[5];
          #pragma unroll
          for (int kw = 0; kw < 5; kw++) w5[kw] = wrow[kw];
          #pragma unroll
          for (int xx = 0; xx < 8; xx++){
            #pragma unroll
            for (int kw = 0; kw < 5; kw++){
              const int xi = xx + kw - 2;
              if ((unsigned)xi < 8u) o[xx] = fmaf(w5[kw], rr[xi], o[xx]);
            }
          }
        }
      }
      const int nb = zy * 8;
      #pragma unroll
      for (int xx = 0; xx < 8; xx++){
        const size_t di = (size_t)(nb + xx)*HD_ + ch0 + ch;
        xabatch[di] += o[xx];            // coalesced across lanes (ch fastest)
      }
    }
    __syncthreads();   // before next half overwrites vol/wv
  }
}

// ---------------- proj GEMM, MFMA bf16 (g now bf16) ----------------
__global__ __launch_bounds__(256) void proj_kernel(
    const float* __restrict__ xa, const unsigned short* __restrict__ g,
    const float* __restrict__ Wp, const float* __restrict__ bp,
    float* __restrict__ out)
{
  __shared__ short As[128][40];
  __shared__ short Bs[128][40];

  const int tid  = threadIdx.x;
  const int row0 = blockIdx.y * 128;
  const int col0 = blockIdx.x * 128;
  const int wave = tid >> 6, lane = tid & 63;
  const int wm = (wave >> 1) * 64, wn = (wave & 1) * 64;
  const int fr = lane & 15, quad = lane >> 4;
  const int sr = tid >> 2;
  const int sk = (tid & 3) * 8;

  f32x4 acc[4][4] = {};

  for (int k0 = 0; k0 < C_; k0 += 32){
    #pragma unroll
    for (int half = 0; half < 2; half++){
      const int r = sr + half*64;
      const size_t aidx = (size_t)(row0 + r)*C_ + k0 + sk;
      float4 x0 = *reinterpret_cast<const float4*>(&xa[aidx]);
      float4 x1 = *reinterpret_cast<const float4*>(&xa[aidx + 4]);
      u16x8 gv = *reinterpret_cast<const u16x8*>(&g[aidx]);
      x0.x*=bf2f(gv[0]); x0.y*=bf2f(gv[1]); x0.z*=bf2f(gv[2]); x0.w*=bf2f(gv[3]);
      x1.x*=bf2f(gv[4]); x1.y*=bf2f(gv[5]); x1.z*=bf2f(gv[6]); x1.w*=bf2f(gv[7]);
      const float* bp2 = &Wp[(size_t)(col0 + r)*C_ + k0 + sk];
      float4 b0 = *reinterpret_cast<const float4*>(bp2);
      float4 b1 = *reinterpret_cast<const float4*>(bp2 + 4);
      *reinterpret_cast<bfrag*>(&As[r][sk]) = cvt8(x0, x1);
      *reinterpret_cast<bfrag*>(&Bs[r][sk]) = cvt8(b0, b1);
    }
    __syncthreads();
    bfrag af[4], bf[4];
    #pragma unroll
    for (int f = 0; f < 4; f++){
      af[f] = *reinterpret_cast<const bfrag*>(&As[wm + f*16 + fr][quad*8]);
      bf[f] = *reinterpret_cast<const bfrag*>(&Bs[wn + f*16 + fr][quad*8]);
    }
    #pragma unroll
    for (int i=0;i<4;i++)
      #pragma unroll
      for (int j=0;j<4;j++)
        acc[i][j] = __builtin_amdgcn_mfma_f32_16x16x32_bf16(af[i], bf[j], acc[i][j], 0, 0, 0);
    __syncthreads();
  }

  #pragma unroll
  for (int i = 0; i < 4; i++){
    const int rowb = row0 + wm + i*16 + quad*4;
    #pragma unroll
    for (int j = 0; j < 4; j++){
      const int col = col0 + wn + j*16 + fr;
      const float bcol = bp[col];
      #pragma unroll
      for (int r = 0; r < 4; r++){
        out[(size_t)(rowb + r)*C_ + col] = acc[i][j][r] + bcol;
      }
    }
  }
}

extern "C" void kernel_launch(void* const* d_in, const int* in_sizes, int n_in,
                              void* d_out, int out_size, void* d_ws, size_t ws_size,
                              hipStream_t stream){
  float* out = (float*)d_out;

  const int expect[11] = {6291456, 6291456, 589824, 1536, 147456, 384, 8000, 64, 384, 384, 196608};
  bool ok = (n_in == 11);
  for (int i = 0; ok && i < 11; i++) ok = (in_sizes[i] == expect[i]);
  if (!ok){
    sentinel_kernel<<<(out_size+255)/256, 256, 0, stream>>>(out, out_size);
    return;
  }

  const float* x    = (const float*)d_in[0];
  const float* y    = (const float*)d_in[1];
  const float* W    = (const float*)d_in[2];
  const float* bq   = (const float*)d_in[3];
  const float* Wp   = (const float*)d_in[4];
  const float* bp   = (const float*)d_in[5];
  const float* dwcw = (const float*)d_in[6];
  const float* dwcb = (const float*)d_in[7];
  const float* pwp  = (const float*)d_in[8];
  const float* scp  = (const float*)d_in[9];
  const float* pe   = (const float*)d_in[10];

  float* ws = (float*)d_ws;
  const size_t SZ = (size_t)M_ * C_;
  // layout (float units): q[0,SZ) k[SZ,2SZ) v_bf16[2SZ,2.5SZ) g_bf16[2.5SZ,3SZ)
  //                       xa[3SZ,4SZ)  (Wb aliases xa start — dead before attn writes xa)
  //                       xb_bf16[4SZ,4.5SZ) yb_bf16[4.5SZ,5SZ) params[5SZ,...)
  float* q  = ws;
  float* k  = ws + SZ;
  unsigned short* v = (unsigned short*)(ws + 2*SZ);
  unsigned short* g = v + SZ;
  float* xa = ws + 3*SZ;
  unsigned short* Wb = (unsigned short*)xa;          // 589824 ushorts, used only pre-attn
  unsigned short* xb = (unsigned short*)(ws + 4*SZ); // SZ ushorts
  unsigned short* yb = xb + SZ;
  float* scale_inv = ws + 5*SZ;
  float* power     = scale_inv + 512;

  param_kernel<<<1, 512, 0, stream>>>(scp, pwp, scale_inv, power);
  cvt_bf16_kernel<<<6432, 256, 0, stream>>>(x, y, W, xb, yb, Wb);
  gemm_qkvg<<<dim3(12, 128), 256, 0, stream>>>(xb, yb, Wb, bq, pe, scale_inv, q, k, v, g);
  attn_kernel<<<dim3(B_*H_), 512, 0, stream>>>(q, k, v, power, xa);
  conv_kernel<<<dim3(B_*H_), 512, 0, stream>>>(v, dwcw, dwcb, xa);
  proj_kernel<<<dim3(3, 128), 256, 0, stream>>>(xa, g, Wp, bp, out);
}